// Round 9
// baseline (365.426 us; speedup 1.0000x reference)
//
#include <hip/hip_runtime.h>

// Rayleigh-Benard tendency kernel, fp32 I/O, fp32 math.
// Layout: state[6][NX][NY][NZ], z contiguous.
// Each thread: 4 consecutive z (float4); z-neighbors via width-32 shuffles.
//
// R9: cooperative LDS staging via global_load_lds. R3-R8 proved the compiler
// always re-sinks register-destined global loads to a 76-VGPR latency-blind
// schedule (~4KB/CU in flight, 2.6 TB/s, ~122 us) and every scheduling hint
// (launch_bounds, sched_barrier, sched_group_barrier) is dissolved; asm
// forcing is container-hostile. global_load_lds has NO destination VGPRs ->
// nothing to sink; each wave issues 21 staging loads back-to-back and drains
// vmcnt ONCE at the barrier. Block = 32x4 (2 waves), tile = x(+-1) x 4y x 128z,
// 84 rows x 512B = 42KB LDS, 3 blocks/CU -> ~129KB in flight per CU during
// staging (vs ~12KB needed for peak BW). Compute reads LDS (conflict-free
// b128), math identical to R3 -> bitwise-identical output.

namespace {
constexpr int NXc = 256, NYc = 256, NZc = 128;
constexpr int FS = NXc * NYc * NZc;   // field stride (elements)
constexpr int XS = NYc * NZc;         // x stride
constexpr int YS = NZc;               // y stride

constexpr float MUc = 1.8e-5f, KTHc = 0.025f, Gc = 9.8f;
constexpr float Rgas = 287.0f;        // CP - CV
constexpr float invCV = 1.0f / 717.0f;

// DX=1/256, DY=1/256, DZ=1/127 — exact in fp32
constexpr float inv2dx = 128.0f, inv2dy = 128.0f, inv2dz = 63.5f;
constexpr float invdx2 = 65536.0f, invdy2 = 65536.0f, invdz2 = 16129.0f;

constexpr int BY = 4;                         // y rows per block
constexpr int RPF = BY + 2 + BY + BY;         // rows per field: 6 center(+halo) + 4 xm + 4 xp = 14
constexpr int TOT_ROWS = 6 * RPF;             // 84
constexpr int ROW_B = NZc * 4;                // 512 bytes per row
constexpr int LDS_B = TOT_ROWS * ROW_B;       // 43008 bytes

typedef float nf4 __attribute__((ext_vector_type(4)));
typedef const __attribute__((address_space(1))) unsigned int gu32;
typedef __attribute__((address_space(3))) unsigned int lu32;
}

__device__ __forceinline__ void st_nt(float4 v, float4* p) {
    nf4 nv;
    nv.x = v.x; nv.y = v.y; nv.z = v.z; nv.w = v.w;
    __builtin_nontemporal_store(nv, reinterpret_cast<nf4*>(p));
}

// Neighbor reads from LDS + z-halo shuffles. Field index fi: u0 v1 w2 r3 T4 c5.
#define LROW(fi, rr) (*(const float4*)(smem + ((fi) * RPF + (rr)) * ROW_B + tx * 16))
#define LOADN(q, fi) \
    const float4 q##_ym = LROW(fi, ty), q##_yp = LROW(fi, 2 + ty); \
    const float4 q##_xm = LROW(fi, 6 + ty), q##_xp = LROW(fi, 10 + ty); \
    const float q##_zm = __shfl_up(q##_c.w, 1, 32); \
    const float q##_zp = __shfl_down(q##_c.x, 1, 32);

// Advection + Laplacian for one component C with z-neighbors PREV/NEXT.
#define ADV_LAP_C(q, C, PREV, NEXT) \
    adv_##q.C = u_c.C * (q##_xp.C - q##_xm.C) * inv2dx \
              + v_c.C * (q##_yp.C - q##_ym.C) * inv2dy \
              + w_c.C * ((NEXT) - (PREV)) * inv2dz; \
    lap_##q.C = (q##_xp.C + q##_xm.C - 2.0f * q##_c.C) * invdx2 \
              + (q##_yp.C + q##_ym.C - 2.0f * q##_c.C) * invdy2 \
              + ((NEXT) + (PREV) - 2.0f * q##_c.C) * invdz2;

#define DERIVS(q) \
    float4 adv_##q, lap_##q; \
    ADV_LAP_C(q, x, q##_zm,  q##_c.y) \
    ADV_LAP_C(q, y, q##_c.x, q##_c.z) \
    ADV_LAP_C(q, z, q##_c.y, q##_c.w) \
    ADV_LAP_C(q, w, q##_c.z, q##_zp)

__global__ __launch_bounds__(128) void rb_kernel(const float* __restrict__ s,
                                                 float* __restrict__ o) {
    extern __shared__ char smem[];

    const int tx = threadIdx.x;                   // 0..31 z-quads
    const int ty = threadIdx.y;                   // 0..3
    const int ty0 = blockIdx.x * BY;
    const int y = ty0 + ty;                       // 0..255
    const int x = blockIdx.y;                     // 0..255

    const int xm = (x == 0) ? NXc - 1 : x - 1;
    const int xp = (x == NXc - 1) ? 0 : x + 1;

    // ---- cooperative staging: 84 rows, 2 rows per wave-issue ----
    // wave = 64 consecutive threads = ty pair; lane = tx + 32*(ty&1).
    // Issue p stages LDS rows {2p, 2p+1}: lanes 0-31 read row 2p's global
    // bytes, lanes 32-63 row 2p+1's; HW writes lane's 16B at ldsbase+lane*16.
    {
        const int wid = ty >> 1;                  // 0..1
        const int half = ty & 1;
        const char* sb = (const char*)s;
        for (int p = wid; p < TOT_ROWS / 2; p += 2) {
            const int R = 2 * p + half;           // LDS row this half stages
            const int f = R / RPF;                // field 0..5
            const int rr = R - f * RPF;           // row-in-field 0..13
            int gx, gy;
            if (rr < BY + 2)      { gx = x;  gy = (ty0 + rr + NYc - 1) & (NYc - 1); }
            else if (rr < 2 * BY + 2) { gx = xm; gy = ty0 + (rr - (BY + 2)); }
            else                  { gx = xp; gy = ty0 + (rr - (2 * BY + 2)); }
            const char* gp = sb + 4u * ((unsigned)f * FS + (unsigned)gx * XS
                                        + (unsigned)gy * YS) + tx * 16;
            __builtin_amdgcn_global_load_lds((gu32*)gp,
                                             (lu32*)(smem + p * 1024),
                                             16, 0, 0);
        }
    }
    __syncthreads();   // drains vmcnt once for the whole 42KB tile

    // ---- centers from LDS (row 1+ty of each field's center slice) ----
    const float4 u_c = LROW(0, 1 + ty), v_c = LROW(1, 1 + ty), w_c = LROW(2, 1 + ty);
    const float4 r_c = LROW(3, 1 + ty), T_c = LROW(4, 1 + ty), c_c = LROW(5, 1 + ty);

    float4 inv_r;
    inv_r.x = 1.0f / r_c.x; inv_r.y = 1.0f / r_c.y;
    inv_r.z = 1.0f / r_c.z; inv_r.w = 1.0f / r_c.w;

    // ---- T (stencil) and pressure gradients ----
    LOADN(T, 4)
    DERIVS(T)
    LOADN(r, 3)

    float4 p_c, p_xm, p_xp, p_ym, p_yp;
#define PC(C) \
    p_c.C  = Rgas * r_c.C  * T_c.C; \
    p_xm.C = Rgas * r_xm.C * T_xm.C;  p_xp.C = Rgas * r_xp.C * T_xp.C; \
    p_ym.C = Rgas * r_ym.C * T_ym.C;  p_yp.C = Rgas * r_yp.C * T_yp.C;
    PC(x) PC(y) PC(z) PC(w)
#undef PC
    const float p_zm = __shfl_up(p_c.w, 1, 32);
    const float p_zp = __shfl_down(p_c.x, 1, 32);

    float4 dpdx, dpdy, dpdz;
#define DP(C) \
    dpdx.C = (p_xp.C - p_xm.C) * inv2dx; \
    dpdy.C = (p_yp.C - p_ym.C) * inv2dy;
    DP(x) DP(y) DP(z) DP(w)
#undef DP
    dpdz.x = (p_c.y - p_zm) * inv2dz;
    dpdz.y = (p_c.z - p_c.x) * inv2dz;
    dpdz.z = (p_c.w - p_c.y) * inv2dz;
    dpdz.w = (p_zp  - p_c.z) * inv2dz;

    // ---- u (+ drou, which needs r_x* and u_x*) ----
    LOADN(u, 0)
    DERIVS(u)
    float4 drou;
#define DR(C) drou.C = -(r_xp.C * u_xp.C - r_xm.C * u_xm.C) * inv2dx;
    DR(x) DR(y) DR(z) DR(w)
#undef DR

    // ---- v ----
    LOADN(v, 1)
    DERIVS(v)

    // ---- w ----
    LOADN(w, 2)
    DERIVS(w)

    // ---- c (advection only; lap_c is dead code, DCE'd) ----
    LOADN(c, 5)
    DERIVS(c)
    (void)lap_c;

    float4 du4, dv4, dw4, dT4, dc4;
#define OUT(C) \
    du4.C = (-dpdx.C + MUc * lap_u.C) * inv_r.C - adv_u.C; \
    dv4.C = (-dpdy.C + MUc * lap_v.C) * inv_r.C - adv_v.C; \
    dw4.C = (-Gc * r_c.C - dpdz.C + MUc * lap_w.C) * inv_r.C - adv_w.C; \
    dT4.C = KTHc * lap_T.C * inv_r.C * invCV - adv_T.C; \
    dc4.C = -adv_c.C;
    OUT(x) OUT(y) OUT(z) OUT(w)
#undef OUT

    // z-wall fixes: tx 0 comp .x is z=0, tx 31 comp .w is z=127
    if (tx == 0) {
        du4.x = 0.0f; dv4.x = 0.0f; dw4.x = 0.0f; dT4.x = 0.0f;
        const float dzc0 = (-3.0f * c_c.x + 4.0f * c_c.y - c_c.z) * inv2dz;
        dc4.x = -(u_c.x * (c_xp.x - c_xm.x) * inv2dx
                + v_c.x * (c_yp.x - c_ym.x) * inv2dy
                + w_c.x * dzc0);
    }
    if (tx == 31) {
        du4.w = 0.0f; dv4.w = 0.0f; dw4.w = 0.0f; dT4.w = 0.0f;
        const float dzcN = (3.0f * c_c.w - 4.0f * c_c.z + c_c.y) * inv2dz;
        dc4.w = -(u_c.w * (c_xp.w - c_xm.w) * inv2dx
                + v_c.w * (c_yp.w - c_ym.w) * inv2dy
                + w_c.w * dzcN);
    }

    const int b4 = (x * XS + y * YS) / 4 + tx;
    float4* o4 = reinterpret_cast<float4*>(o);
    const int fs4 = FS / 4;
    st_nt(du4,  o4 + b4);
    st_nt(dv4,  o4 + b4 + fs4);
    st_nt(dw4,  o4 + b4 + 2 * fs4);
    st_nt(drou, o4 + b4 + 3 * fs4);
    st_nt(dT4,  o4 + b4 + 4 * fs4);
    st_nt(dc4,  o4 + b4 + 5 * fs4);
}

extern "C" void kernel_launch(void* const* d_in, const int* in_sizes, int n_in,
                              void* d_out, int out_size, void* d_ws, size_t ws_size,
                              hipStream_t stream) {
    (void)in_sizes; (void)n_in; (void)d_ws; (void)ws_size; (void)out_size;
    const float* s = (const float*)d_in[0];
    float* o = (float*)d_out;

    dim3 block(32, BY, 1);          // 32 z-quads x 4 y rows = 128 threads (2 waves)
    dim3 grid(NYc / BY, NXc, 1);    // (y tiles, x)
    rb_kernel<<<grid, block, LDS_B, stream>>>(s, o);
}